// Round 6
// baseline (371.056 us; speedup 1.0000x reference)
//
#include <hip/hip_runtime.h>
#include <hip/hip_bf16.h>
#include <stdint.h>

#define D_IN 1024
#define D_K  128
#define NBATCH 8
#define SEQ  4096
#define MROWS (NBATCH * SEQ)

typedef __attribute__((ext_vector_type(8))) short bf16x8;
typedef __attribute__((ext_vector_type(4))) float f32x4;

__device__ __forceinline__ unsigned short f32_to_bf16(float x) {
    union { float f; uint32_t u; } v; v.f = x;
    uint32_t r = 0x7FFFu + ((v.u >> 16) & 1u);
    return (unsigned short)((v.u + r) >> 16);
}

__device__ __forceinline__ bf16x8 cvt8(float4 lo, float4 hi) {
    bf16x8 r;
    r[0] = (short)f32_to_bf16(lo.x); r[1] = (short)f32_to_bf16(lo.y);
    r[2] = (short)f32_to_bf16(lo.z); r[3] = (short)f32_to_bf16(lo.w);
    r[4] = (short)f32_to_bf16(hi.x); r[5] = (short)f32_to_bf16(hi.y);
    r[6] = (short)f32_to_bf16(hi.z); r[7] = (short)f32_to_bf16(hi.w);
    return r;
}

// ---------------- W pre-convert (unchanged, passing) ----------------
__global__ __launch_bounds__(256)
void wconv_kernel(const float* __restrict__ Wq, const float* __restrict__ Wk,
                  const float* __restrict__ Wv, unsigned short* __restrict__ Wt)
{
    const int t  = blockIdx.x * 256 + threadIdx.x;
    const int n  = t & 127;
    const int kc = (t >> 7) & 127;
    const int p  = t >> 14;
    const float* __restrict__ W = (p == 0) ? Wq : (p == 1) ? Wk : Wv;
    const float sc = (p == 0) ? (1.44269504088896f * 0.0883883476483184f) : 1.0f;
    const float4* src = reinterpret_cast<const float4*>(W + (size_t)n * D_IN + kc * 8);
    float4 a = src[0], b = src[1];
    uint4 o;
    o.x = (uint32_t)f32_to_bf16(a.x * sc) | ((uint32_t)f32_to_bf16(a.y * sc) << 16);
    o.y = (uint32_t)f32_to_bf16(a.z * sc) | ((uint32_t)f32_to_bf16(a.w * sc) << 16);
    o.z = (uint32_t)f32_to_bf16(b.x * sc) | ((uint32_t)f32_to_bf16(b.y * sc) << 16);
    o.w = (uint32_t)f32_to_bf16(b.z * sc) | ((uint32_t)f32_to_bf16(b.w * sc) << 16);
    *reinterpret_cast<uint4*>(Wt + (size_t)t * 8) = o;
}

// ================= DIAGNOSTIC DISPATCHES (dummy output into kh region) =====

// diag0: pure row-linear stream of X_q. Block = 32 rows, wave = 8 rows,
// lane reads 4x16B (1KB-contiguous per instr), depth-2 row pipeline.
__global__ __launch_bounds__(256)
void diag_stream(const float* __restrict__ X, f32x4* __restrict__ dummy)
{
    const int tid  = threadIdx.x;
    const int lane = tid & 63;
    const int wave = tid >> 6;
    const int r0   = blockIdx.x * 32 + wave * 8;

    const char* base = reinterpret_cast<const char*>(X) + (size_t)r0 * 4096 + lane * 16;
    f32x4 s0 = {0,0,0,0}, s1 = {0,0,0,0}, s2 = {0,0,0,0}, s3 = {0,0,0,0};

    float4 a0 = *reinterpret_cast<const float4*>(base);
    float4 a1 = *reinterpret_cast<const float4*>(base + 1024);
    float4 a2 = *reinterpret_cast<const float4*>(base + 2048);
    float4 a3 = *reinterpret_cast<const float4*>(base + 3072);
    #pragma unroll
    for (int r = 0; r < 8; ++r) {
        float4 c0 = a0, c1 = a1, c2 = a2, c3 = a3;
        if (r < 7) {
            const char* np = base + (size_t)(r + 1) * 4096;
            a0 = *reinterpret_cast<const float4*>(np);
            a1 = *reinterpret_cast<const float4*>(np + 1024);
            a2 = *reinterpret_cast<const float4*>(np + 2048);
            a3 = *reinterpret_cast<const float4*>(np + 3072);
        }
        s0 += (f32x4){c0.x, c0.y, c0.z, c0.w};
        s1 += (f32x4){c1.x, c1.y, c1.z, c1.w};
        s2 += (f32x4){c2.x, c2.y, c2.z, c2.w};
        s3 += (f32x4){c3.x, c3.y, c3.z, c3.w};
    }
    dummy[(size_t)blockIdx.x * 256 + tid] = s0 + s1 + s2 + s3;
}

// diag1: stream + LDS stage/swizzle + LDS readback + MFMA (no Wt loads).
__global__ __launch_bounds__(256, 2)
void diag_ldsmfma(const float* __restrict__ X, f32x4* __restrict__ dummy)
{
    __shared__ unsigned short As[32 * 1024];
    const int tid  = threadIdx.x;
    const int lane = tid & 63;
    const int wave = tid >> 6;
    const int lrow = lane & 15;
    const int g    = lane >> 4;
    const int wr   = (wave >> 1) * 16;

    {   // stage: identical to proj phase 1
        const int r0 = wave * 8;
        const char* rowp = reinterpret_cast<const char*>(
            X + (size_t)(blockIdx.x * 32 + r0) * D_IN) + lane * 32;
        float4 a0 = *reinterpret_cast<const float4*>(rowp);
        float4 a1 = *reinterpret_cast<const float4*>(rowp + 16);
        float4 a2 = *reinterpret_cast<const float4*>(rowp + 2048);
        float4 a3 = *reinterpret_cast<const float4*>(rowp + 2048 + 16);
        #pragma unroll
        for (int i = 0; i < 8; ++i) {
            float4 c0 = a0, c1 = a1, c2 = a2, c3 = a3;
            if (i < 7) {
                const char* np = rowp + (size_t)(i + 1) * 4096;
                a0 = *reinterpret_cast<const float4*>(np);
                a1 = *reinterpret_cast<const float4*>(np + 16);
                a2 = *reinterpret_cast<const float4*>(np + 2048);
                a3 = *reinterpret_cast<const float4*>(np + 2048 + 16);
            }
            const int r = r0 + i;
            char* b = reinterpret_cast<char*>(As) + r * 2048;
            const int swz = (r & 7) << 4;
            *reinterpret_cast<bf16x8*>(b + ((lane * 16) ^ swz)) = cvt8(c0, c1);
            *reinterpret_cast<bf16x8*>(b + ((1024 + lane * 16) ^ swz)) = cvt8(c2, c3);
        }
    }
    __syncthreads();

    f32x4 acc[4];
    #pragma unroll
    for (int ni = 0; ni < 4; ++ni) acc[ni] = (f32x4){0,0,0,0};
    const int arow = wr + lrow;
    const char* abase = reinterpret_cast<const char*>(As) + arow * 2048;
    const int aswz = (arow & 7) << 4;

    bf16x8 afc = *reinterpret_cast<const bf16x8*>(abase + ((g * 16) ^ aswz));
    #pragma unroll 4
    for (int t = 0; t < 32; ++t) {
        bf16x8 afn;
        if (t < 31)
            afn = *reinterpret_cast<const bf16x8*>(abase + (((t + 1) * 64 + g * 16) ^ aswz));
        acc[0] = __builtin_amdgcn_mfma_f32_16x16x32_bf16(afc, afc, acc[0], 0, 0, 0);
        acc[1] = __builtin_amdgcn_mfma_f32_16x16x32_bf16(afc, afc, acc[1], 0, 0, 0);
        acc[2] = __builtin_amdgcn_mfma_f32_16x16x32_bf16(afc, afc, acc[2], 0, 0, 0);
        acc[3] = __builtin_amdgcn_mfma_f32_16x16x32_bf16(afc, afc, acc[3], 0, 0, 0);
        afc = afn;
    }
    dummy[(size_t)blockIdx.x * 256 + tid] = acc[0] + acc[1] + acc[2] + acc[3];
}

// diag2: the FULL round-5 proj body for p=0 (incl. Wt loads), dummy epilogue.
__global__ __launch_bounds__(256, 2)
void diag_full(const float* __restrict__ X, const unsigned short* __restrict__ Wt,
               f32x4* __restrict__ dummy)
{
    __shared__ unsigned short As[32 * 1024];
    const int tid  = threadIdx.x;
    const int lane = tid & 63;
    const int wave = tid >> 6;
    const int lrow = lane & 15;
    const int g    = lane >> 4;
    const int wr   = (wave >> 1) * 16;
    const int wc   = (wave & 1) * 64;

    {
        const int r0 = wave * 8;
        const char* rowp = reinterpret_cast<const char*>(
            X + (size_t)(blockIdx.x * 32 + r0) * D_IN) + lane * 32;
        float4 a0 = *reinterpret_cast<const float4*>(rowp);
        float4 a1 = *reinterpret_cast<const float4*>(rowp + 16);
        float4 a2 = *reinterpret_cast<const float4*>(rowp + 2048);
        float4 a3 = *reinterpret_cast<const float4*>(rowp + 2048 + 16);
        #pragma unroll
        for (int i = 0; i < 8; ++i) {
            float4 c0 = a0, c1 = a1, c2 = a2, c3 = a3;
            if (i < 7) {
                const char* np = rowp + (size_t)(i + 1) * 4096;
                a0 = *reinterpret_cast<const float4*>(np);
                a1 = *reinterpret_cast<const float4*>(np + 16);
                a2 = *reinterpret_cast<const float4*>(np + 2048);
                a3 = *reinterpret_cast<const float4*>(np + 2048 + 16);
            }
            const int r = r0 + i;
            char* b = reinterpret_cast<char*>(As) + r * 2048;
            const int swz = (r & 7) << 4;
            *reinterpret_cast<bf16x8*>(b + ((lane * 16) ^ swz)) = cvt8(c0, c1);
            *reinterpret_cast<bf16x8*>(b + ((1024 + lane * 16) ^ swz)) = cvt8(c2, c3);
        }
    }
    __syncthreads();

    f32x4 acc[4];
    #pragma unroll
    for (int ni = 0; ni < 4; ++ni) acc[ni] = (f32x4){0,0,0,0};
    const int arow = wr + lrow;
    const char* abase = reinterpret_cast<const char*>(As) + arow * 2048;
    const int aswz = (arow & 7) << 4;

    bf16x8 afc = *reinterpret_cast<const bf16x8*>(abase + ((g * 16) ^ aswz));
    bf16x8 b0, b1, b2, b3;
    {
        const unsigned short* wb = Wt + ((size_t)g * 128 + wc + lrow) * 8;
        b0 = *reinterpret_cast<const bf16x8*>(wb);
        b1 = *reinterpret_cast<const bf16x8*>(wb + 128);
        b2 = *reinterpret_cast<const bf16x8*>(wb + 256);
        b3 = *reinterpret_cast<const bf16x8*>(wb + 384);
    }
    #pragma unroll 4
    for (int t = 0; t < 32; ++t) {
        bf16x8 afn, n0, n1, n2, n3;
        if (t < 31) {
            afn = *reinterpret_cast<const bf16x8*>(abase + (((t + 1) * 64 + g * 16) ^ aswz));
            const unsigned short* wb = Wt + ((size_t)((t + 1) * 4 + g) * 128 + wc + lrow) * 8;
            n0 = *reinterpret_cast<const bf16x8*>(wb);
            n1 = *reinterpret_cast<const bf16x8*>(wb + 128);
            n2 = *reinterpret_cast<const bf16x8*>(wb + 256);
            n3 = *reinterpret_cast<const bf16x8*>(wb + 384);
        }
        acc[0] = __builtin_amdgcn_mfma_f32_16x16x32_bf16(afc, b0, acc[0], 0, 0, 0);
        acc[1] = __builtin_amdgcn_mfma_f32_16x16x32_bf16(afc, b1, acc[1], 0, 0, 0);
        acc[2] = __builtin_amdgcn_mfma_f32_16x16x32_bf16(afc, b2, acc[2], 0, 0, 0);
        acc[3] = __builtin_amdgcn_mfma_f32_16x16x32_bf16(afc, b3, acc[3], 0, 0, 0);
        afc = afn; b0 = n0; b1 = n1; b2 = n2; b3 = n3;
    }
    dummy[(size_t)blockIdx.x * 256 + tid] = acc[0] + acc[1] + acc[2] + acc[3];
}

// ---------------- projection GEMM (round-5, passing, unchanged) ----------------
#define RBM 32
#define NT  32

__global__ __launch_bounds__(256, 2)
void proj_kernel(const float* __restrict__ Xq, const float* __restrict__ Xk,
                 const float* __restrict__ Xv,
                 const unsigned short* __restrict__ Wt,
                 unsigned short* __restrict__ qh, unsigned short* __restrict__ kh,
                 unsigned short* __restrict__ vhT)
{
    const int p = blockIdx.y;
    const float* __restrict__ X = (p == 0) ? Xq : (p == 1) ? Xk : Xv;
    const unsigned short* __restrict__ Wtp = Wt + (size_t)p * 128 * 128 * 8;

    __shared__ unsigned short As[RBM * 1024];

    const int tid  = threadIdx.x;
    const int lane = tid & 63;
    const int wave = tid >> 6;
    const int lrow = lane & 15;
    const int g    = lane >> 4;
    const int wr   = (wave >> 1) * 16;
    const int wc   = (wave & 1) * 64;
    const int wbase = blockIdx.x * RBM;

    {
        const int r0 = wave * 8;
        const char* rowp = reinterpret_cast<const char*>(
            X + (size_t)(wbase + r0) * D_IN) + lane * 32;
        float4 a0 = *reinterpret_cast<const float4*>(rowp);
        float4 a1 = *reinterpret_cast<const float4*>(rowp + 16);
        float4 a2 = *reinterpret_cast<const float4*>(rowp + 2048);
        float4 a3 = *reinterpret_cast<const float4*>(rowp + 2048 + 16);
        #pragma unroll
        for (int i = 0; i < 8; ++i) {
            float4 c0 = a0, c1 = a1, c2 = a2, c3 = a3;
            if (i < 7) {
                const char* np = rowp + (size_t)(i + 1) * 4096;
                a0 = *reinterpret_cast<const float4*>(np);
                a1 = *reinterpret_cast<const float4*>(np + 16);
                a2 = *reinterpret_cast<const float4*>(np + 2048);
                a3 = *reinterpret_cast<const float4*>(np + 2048 + 16);
            }
            const int r = r0 + i;
            char* base = reinterpret_cast<char*>(As) + r * 2048;
            const int swz = (r & 7) << 4;
            *reinterpret_cast<bf16x8*>(base + ((lane * 16) ^ swz)) = cvt8(c0, c1);
            *reinterpret_cast<bf16x8*>(base + ((1024 + lane * 16) ^ swz)) = cvt8(c2, c3);
        }
    }
    __syncthreads();

    f32x4 acc[4];
    #pragma unroll
    for (int ni = 0; ni < 4; ++ni) acc[ni] = (f32x4){0.f, 0.f, 0.f, 0.f};

    const int arow = wr + lrow;
    const char* abase = reinterpret_cast<const char*>(As) + arow * 2048;
    const int aswz = (arow & 7) << 4;

    bf16x8 afc = *reinterpret_cast<const bf16x8*>(abase + ((g * 16) ^ aswz));
    bf16x8 b0, b1, b2, b3;
    {
        const unsigned short* wb = Wtp + ((size_t)g * 128 + wc + lrow) * 8;
        b0 = *reinterpret_cast<const bf16x8*>(wb);
        b1 = *reinterpret_cast<const bf16x8*>(wb + 128);
        b2 = *reinterpret_cast<const bf16x8*>(wb + 256);
        b3 = *reinterpret_cast<const bf16x8*>(wb + 384);
    }

    #pragma unroll 4
    for (int t = 0; t < NT; ++t) {
        bf16x8 afn, n0, n1, n2, n3;
        if (t < NT - 1) {
            afn = *reinterpret_cast<const bf16x8*>(
                abase + (((t + 1) * 64 + g * 16) ^ aswz));
            const unsigned short* wb =
                Wtp + ((size_t)((t + 1) * 4 + g) * 128 + wc + lrow) * 8;
            n0 = *reinterpret_cast<const bf16x8*>(wb);
            n1 = *reinterpret_cast<const bf16x8*>(wb + 128);
            n2 = *reinterpret_cast<const bf16x8*>(wb + 256);
            n3 = *reinterpret_cast<const bf16x8*>(wb + 384);
        }
        acc[0] = __builtin_amdgcn_mfma_f32_16x16x32_bf16(afc, b0, acc[0], 0, 0, 0);
        acc[1] = __builtin_amdgcn_mfma_f32_16x16x32_bf16(afc, b1, acc[1], 0, 0, 0);
        acc[2] = __builtin_amdgcn_mfma_f32_16x16x32_bf16(afc, b2, acc[2], 0, 0, 0);
        acc[3] = __builtin_amdgcn_mfma_f32_16x16x32_bf16(afc, b3, acc[3], 0, 0, 0);
        afc = afn; b0 = n0; b1 = n1; b2 = n2; b3 = n3;
    }

    if (p < 2) {
        unsigned short* __restrict__ Y = (p == 0) ? qh : kh;
        const int rbase = wbase + wr + g * 4;
        #pragma unroll
        for (int ni = 0; ni < 4; ++ni) {
            const int n = wc + ni * 16 + lrow;
            #pragma unroll
            for (int r = 0; r < 4; ++r)
                Y[(size_t)(rbase + r) * D_K + n] = f32_to_bf16(acc[ni][r]);
        }
    } else {
        const int b  = wbase >> 12;
        const int s  = (wbase & 4095) + wr + g * 4;
        #pragma unroll
        for (int ni = 0; ni < 4; ++ni) {
            const int d = wc + ni * 16 + lrow;
            uint2 t;
            t.x = (uint32_t)f32_to_bf16(acc[ni][0]) |
                  ((uint32_t)f32_to_bf16(acc[ni][1]) << 16);
            t.y = (uint32_t)f32_to_bf16(acc[ni][2]) |
                  ((uint32_t)f32_to_bf16(acc[ni][3]) << 16);
            *reinterpret_cast<uint2*>(vhT + ((size_t)(b * D_K + d) << 12) + s) = t;
        }
    }
}

// ---------------- flash attention (round-5, passing, unchanged) ----------------
#define KVB 64

__global__ __launch_bounds__(256)
void attn_kernel(const unsigned short* __restrict__ qh,
                 const unsigned short* __restrict__ kh,
                 const unsigned short* __restrict__ vhT,
                 float* __restrict__ out)
{
    __shared__ unsigned short Ks[KVB * D_K];
    __shared__ unsigned short Vs[D_K * KVB];
    __shared__ unsigned short Ps[4][32 * KVB];

    const int tid  = threadIdx.x;
    const int lane = tid & 63;
    const int wave = tid >> 6;
    const int b    = blockIdx.x & 7;
    const int qt   = blockIdx.x >> 3;
    const int q0   = qt * 128 + wave * 32;
    const int lrow = lane & 15;
    const int lk16 = (lane >> 4) * 16;

    bf16x8 qf[2][4];
    #pragma unroll
    for (int mi = 0; mi < 2; ++mi) {
        const char* base = reinterpret_cast<const char*>(
            qh + (size_t)(b * SEQ + q0 + mi * 16 + lrow) * D_K);
        #pragma unroll
        for (int ks = 0; ks < 4; ++ks)
            qf[mi][ks] = *reinterpret_cast<const bf16x8*>(base + ks * 64 + lk16);
    }

    f32x4 o[2][8];
    #pragma unroll
    for (int mi = 0; mi < 2; ++mi)
        #pragma unroll
        for (int df = 0; df < 8; ++df)
            o[mi][df] = (f32x4){0.f, 0.f, 0.f, 0.f};
    float lsum[2][4];
    #pragma unroll
    for (int mi = 0; mi < 2; ++mi)
        #pragma unroll
        for (int r = 0; r < 4; ++r) lsum[mi][r] = 0.f;

    const unsigned short* __restrict__ Kb = kh + (size_t)b * SEQ * D_K;
    const unsigned short* __restrict__ Vb = vhT + (size_t)b * D_K * SEQ;
    unsigned short* const Pw = Ps[wave];

    for (int s0 = 0; s0 < SEQ; s0 += KVB) {
        __syncthreads();
        #pragma unroll
        for (int i = 0; i < 4; ++i) {
            int slot = i * 256 + tid;
            int row  = slot >> 4;
            int cb   = (slot & 15) * 16;
            uint4 t = *reinterpret_cast<const uint4*>(
                reinterpret_cast<const char*>(Kb + (size_t)(s0 + row) * D_K) + cb);
            *reinterpret_cast<uint4*>(reinterpret_cast<char*>(Ks) +
                row * 256 + (cb ^ ((row & 7) << 4))) = t;
        }
        #pragma unroll
        for (int i = 0; i < 4; ++i) {
            int slot = i * 256 + tid;
            int row  = slot >> 3;
            int cb   = (slot & 7) * 16;
            uint4 t = *reinterpret_cast<const uint4*>(
                reinterpret_cast<const char*>(Vb + (size_t)row * SEQ + s0) + cb);
            *reinterpret_cast<uint4*>(reinterpret_cast<char*>(Vs) +
                row * 128 + (cb ^ ((row & 7) << 4))) = t;
        }
        __syncthreads();

        f32x4 sc[2][4];
        #pragma unroll
        for (int mi = 0; mi < 2; ++mi)
            #pragma unroll
            for (int sf = 0; sf < 4; ++sf)
                sc[mi][sf] = (f32x4){0.f, 0.f, 0.f, 0.f};

        #pragma unroll
        for (int ks = 0; ks < 4; ++ks) {
            bf16x8 kf[4];
            #pragma unroll
            for (int sf = 0; sf < 4; ++sf) {
                int row = sf * 16 + lrow;
                kf[sf] = *reinterpret_cast<const bf16x8*>(
                    reinterpret_cast<const char*>(Ks) + row * 256 +
                    ((ks * 64 + lk16) ^ ((row & 7) << 4)));
            }
            #pragma unroll
            for (int mi = 0; mi < 2; ++mi)
                #pragma unroll
                for (int sf = 0; sf < 4; ++sf)
                    sc[mi][sf] = __builtin_amdgcn_mfma_f32_16x16x32_bf16(
                        qf[mi][ks], kf[sf], sc[mi][sf], 0, 0, 0);
        }

        #pragma unroll
        for (int mi = 0; mi < 2; ++mi) {
            #pragma unroll
            for (int sf = 0; sf < 4; ++sf) {
                #pragma unroll
                for (int r = 0; r < 4; ++r) {
                    float pv = exp2f(sc[mi][sf][r]);
                    lsum[mi][r] += pv;
                    int prow = mi * 16 + ((lane >> 4) << 2) + r;
                    int pcol = (sf * 16 + lrow) * 2;
                    *reinterpret_cast<unsigned short*>(
                        reinterpret_cast<char*>(Pw) + prow * 128 +
                        (pcol ^ ((prow & 7) << 4))) = f32_to_bf16(pv);
                }
            }
        }

        #pragma unroll
        for (int ks = 0; ks < 2; ++ks) {
            bf16x8 pf[2];
            #pragma unroll
            for (int mi = 0; mi < 2; ++mi) {
                int row = mi * 16 + lrow;
                pf[mi] = *reinterpret_cast<const bf16x8*>(
                    reinterpret_cast<const char*>(Pw) + row * 128 +
                    ((ks * 64 + lk16) ^ ((row & 7) << 4)));
            }
            #pragma unroll
            for (int df = 0; df < 8; ++df) {
                int vrow = df * 16 + lrow;
                bf16x8 vf = *reinterpret_cast<const bf16x8*>(
                    reinterpret_cast<const char*>(Vs) + vrow * 128 +
                    ((ks * 64 + lk16) ^ ((vrow & 7) << 4)));
                #pragma unroll
                for (int mi = 0; mi < 2; ++mi)
                    o[mi][df] = __builtin_amdgcn_mfma_f32_16x16x32_bf16(
                        pf[mi], vf, o[mi][df], 0, 0, 0);
            }
        }
    }

    #pragma unroll
    for (int mi = 0; mi < 2; ++mi) {
        #pragma unroll
        for (int r = 0; r < 4; ++r) {
            float s = lsum[mi][r];
            s += __shfl_xor(s, 1);
            s += __shfl_xor(s, 2);
            s += __shfl_xor(s, 4);
            s += __shfl_xor(s, 8);
            float inv = 1.0f / s;
            const int row = q0 + mi * 16 + ((lane >> 4) << 2) + r;
            float* ob = out + (size_t)(b * SEQ + row) * D_K + lrow;
            #pragma unroll
            for (int df = 0; df < 8; ++df)
                ob[df * 16] = o[mi][df][r] * inv;
        }
    }
}

extern "C" void kernel_launch(void* const* d_in, const int* in_sizes, int n_in,
                              void* d_out, int out_size, void* d_ws, size_t ws_size,
                              hipStream_t stream)
{
    (void)in_sizes; (void)n_in; (void)out_size; (void)ws_size;
    const float* q  = (const float*)d_in[0];
    const float* k  = (const float*)d_in[1];
    const float* v  = (const float*)d_in[2];
    const float* Wq = (const float*)d_in[3];
    const float* Wk = (const float*)d_in[4];
    const float* Wv = (const float*)d_in[5];

    unsigned short* qh  = (unsigned short*)d_ws;                 // [32768][128] bf16
    unsigned short* kh  = qh + (size_t)MROWS * D_K;              // [32768][128] bf16
    unsigned short* vhT = kh + (size_t)MROWS * D_K;              // [8][128][4096] bf16
    unsigned short* Wt  = vhT + (size_t)MROWS * D_K;             // [3][128][128][8] bf16

    // diagnostics dump into kh region (fully overwritten by proj afterwards)
    f32x4* dummy = (f32x4*)kh;

    wconv_kernel<<<dim3(192), 256, 0, stream>>>(Wq, Wk, Wv, Wt);
    diag_stream <<<dim3(1024), 256, 0, stream>>>(q, dummy);
    diag_ldsmfma<<<dim3(1024), 256, 0, stream>>>(q, dummy);
    diag_full   <<<dim3(1024), 256, 0, stream>>>(q, Wt, dummy);
    proj_kernel<<<dim3(MROWS / RBM, 3), 256, 0, stream>>>(q, k, v, Wt, qh, kh, vhT);
    attn_kernel<<<dim3(NBATCH * (SEQ / 128)), 256, 0, stream>>>(qh, kh, vhT, (float*)d_out);
}